// Round 7
// baseline (710.240 us; speedup 1.0000x reference)
//
#include <hip/hip_runtime.h>
#include <math.h>

#define BB 2
#define SS 2048
#define EE 2048
#define HH 16
#define KVHH 4
#define DD 128
#define GG (HH / KVHH)
#define KVN (KVHH * DD)   // 512
#define SCALE 0.08838834764831843f
// SCALE * log2(e): scores land in log2 domain -> exp2f softmax
#define QSCALE (0.08838834764831843f * 1.4426950408889634f)

typedef __attribute__((ext_vector_type(8))) short bf16x8;
typedef __attribute__((ext_vector_type(4))) float f32x4;
typedef unsigned short u16;
typedef unsigned int u32;

__device__ __forceinline__ u16 f2bf(float f) {
    union { float f; u32 u; } x; x.f = f;
    u32 r = x.u + 0x7fff + ((x.u >> 16) & 1);   // RNE
    return (u16)(r >> 16);
}
// HW packed f32->bf16 (RNE), 1 instr for 2 values: lo=bf16(a), hi=bf16(b)
__device__ __forceinline__ u32 cvtpk_bf16(float a, float b) {
    u32 r;
    asm("v_cvt_pk_bf16_f32 %0, %1, %2" : "=v"(r) : "v"(a), "v"(b));
    return r;
}

__device__ __forceinline__ void gload_lds16(const void* g, void* l) {
    __builtin_amdgcn_global_load_lds(
        (const __attribute__((address_space(1))) u32*)g,
        (__attribute__((address_space(3))) u32*)l, 16, 0, 0);
}

// raw workgroup barrier: NO implicit vmcnt/lgkmcnt drain (unlike __syncthreads).
#define RBAR asm volatile("s_barrier" ::: "memory")

// ---------------------------------------------------------------------------
// Fused fp32->bf16 cast of all 5 tensors. Block-granular segments, 1024 el/blk.
// ---------------------------------------------------------------------------
#define NB_X  8192      // B*S*E / 1024
#define NB_QO 4096      // E*E / 1024
#define NB_KV 1024      // KVN*E / 1024
__global__ __launch_bounds__(256) void cast_all(const float* __restrict__ x,
                                                const float* __restrict__ wq,
                                                const float* __restrict__ wk,
                                                const float* __restrict__ wv,
                                                const float* __restrict__ wo,
                                                u16* __restrict__ xb, u16* __restrict__ wqb,
                                                u16* __restrict__ wkb, u16* __restrict__ wvb,
                                                u16* __restrict__ wob) {
    int bid = blockIdx.x;
    const float* src; u16* dst; int off;
    if (bid < NB_X)                       { src = x;  dst = xb;  off = bid * 1024; }
    else if (bid < NB_X + NB_QO)          { src = wq; dst = wqb; off = (bid - NB_X) * 1024; }
    else if (bid < NB_X + NB_QO + NB_KV)  { src = wk; dst = wkb; off = (bid - NB_X - NB_QO) * 1024; }
    else if (bid < NB_X + NB_QO + 2*NB_KV){ src = wv; dst = wvb; off = (bid - NB_X - NB_QO - NB_KV) * 1024; }
    else                                  { src = wo; dst = wob; off = (bid - NB_X - NB_QO - 2*NB_KV) * 1024; }
    int i = off + threadIdx.x * 4;
    float4 v = *(const float4*)&src[i];
    ushort4 o;
    o.x = f2bf(v.x); o.y = f2bf(v.y); o.z = f2bf(v.z); o.w = f2bf(v.w);
    *(ushort4*)&dst[i] = o;
}

// ---------------------------------------------------------------------------
// m97-structure MFMA GEMM (PROVEN: 83 us MODE5 / ~55 us MODE0 in round 3).
// C[M,N] = A[M,K] @ B[N,K]^T, bf16 in, fp32 acc.
// MODE 0: fp32 row-major C
// MODE 5: fused QKV epilogue (B = [Wq;Wk;Wv] concat, N=3072):
//   n<2048      -> Qg bf16 [M][2048], scaled by QSCALE
//   2048..2559  -> Kg bf16 [M][512]
//   2560..3071  -> Vt bf16 [(b*KVN + d)][S]
// ---------------------------------------------------------------------------
template <int MODE>
__global__ __launch_bounds__(256) void gemm_mfma(const u16* __restrict__ A,
                                                 const u16* __restrict__ B,
                                                 void* __restrict__ Cv,
                                                 void* __restrict__ Cv2,
                                                 void* __restrict__ Cv3,
                                                 int M, int N, int K) {
    __shared__ __align__(16) u16 As[128 * 32];
    __shared__ __align__(16) u16 Bs[128 * 32];
    const int tid  = threadIdx.x;
    const int w    = tid >> 6;
    const int lane = tid & 63;
    const int l16  = lane & 15;
    const int quad = lane >> 4;
    const int wm = (w >> 1) * 64;
    const int wn = (w & 1) * 64;
    const int m0 = blockIdx.y * 128;
    const int n0 = blockIdx.x * 128;

    const int r0 = tid >> 2,           ko0 = (tid & 3) * 8;
    const int r1 = (256 + tid) >> 2,   ko1 = (tid & 3) * 8;
    u16* ldsA0 = &As[(size_t)(w * 64) * 8];
    u16* ldsA1 = &As[(size_t)(256 + w * 64) * 8];
    u16* ldsB0 = &Bs[(size_t)(w * 64) * 8];
    u16* ldsB1 = &Bs[(size_t)(256 + w * 64) * 8];

    f32x4 acc[4][4];
#pragma unroll
    for (int i = 0; i < 4; ++i)
#pragma unroll
        for (int j = 0; j < 4; ++j) acc[i][j] = (f32x4){0.f, 0.f, 0.f, 0.f};

    for (int k0 = 0; k0 < K; k0 += 32) {
        __syncthreads();
        gload_lds16(A + (size_t)(m0 + r0) * K + k0 + ko0, ldsA0);
        gload_lds16(A + (size_t)(m0 + r1) * K + k0 + ko1, ldsA1);
        gload_lds16(B + (size_t)(n0 + r0) * K + k0 + ko0, ldsB0);
        gload_lds16(B + (size_t)(n0 + r1) * K + k0 + ko1, ldsB1);
        __syncthreads();

        bf16x8 af[4], bfr[4];
#pragma unroll
        for (int i = 0; i < 4; ++i)
            af[i] = *(const bf16x8*)&As[(wm + i * 16 + l16) * 32 + quad * 8];
#pragma unroll
        for (int j = 0; j < 4; ++j)
            bfr[j] = *(const bf16x8*)&Bs[(wn + j * 16 + l16) * 32 + quad * 8];
#pragma unroll
        for (int i = 0; i < 4; ++i)
#pragma unroll
            for (int j = 0; j < 4; ++j)
                acc[i][j] = __builtin_amdgcn_mfma_f32_16x16x32_bf16(af[i], bfr[j], acc[i][j], 0, 0, 0);
    }

    if (MODE == 0) {
        float* C = (float*)Cv;
#pragma unroll
        for (int i = 0; i < 4; ++i)
#pragma unroll
            for (int j = 0; j < 4; ++j)
#pragma unroll
                for (int reg = 0; reg < 4; ++reg)
                    C[(size_t)(m0 + wm + i * 16 + quad * 4 + reg) * N + n0 + wn + j * 16 + l16] =
                        acc[i][j][reg];
    } else {   // MODE 5
        if (n0 < 2048) {
            u16* C = (u16*)Cv;   // Qg [M][2048], QSCALE folded in
#pragma unroll
            for (int i = 0; i < 4; ++i)
#pragma unroll
                for (int j = 0; j < 4; ++j)
#pragma unroll
                    for (int reg = 0; reg < 4; ++reg)
                        C[(size_t)(m0 + wm + i * 16 + quad * 4 + reg) * 2048 + n0 + wn + j * 16 + l16] =
                            f2bf(acc[i][j][reg] * QSCALE);
        } else if (n0 < 2560) {
            u16* C = (u16*)Cv2;  // Kg [M][512]
            const int nb = n0 - 2048;
#pragma unroll
            for (int i = 0; i < 4; ++i)
#pragma unroll
                for (int j = 0; j < 4; ++j)
#pragma unroll
                    for (int reg = 0; reg < 4; ++reg)
                        C[(size_t)(m0 + wm + i * 16 + quad * 4 + reg) * KVN + nb + wn + j * 16 + l16] =
                            f2bf(acc[i][j][reg]);
        } else {
            u16* C2 = (u16*)Cv3;  // Vt [(b*KVN + d)][S]
            const int db = n0 - 2560;
#pragma unroll
            for (int i = 0; i < 4; ++i) {
                const int m = m0 + wm + i * 16 + quad * 4;
                const int bb = m >> 11;
                const int s  = m & (SS - 1);
#pragma unroll
                for (int j = 0; j < 4; ++j) {
                    const int d = db + wn + j * 16 + l16;
                    ushort4 p;
                    p.x = f2bf(acc[i][j][0]); p.y = f2bf(acc[i][j][1]);
                    p.z = f2bf(acc[i][j][2]); p.w = f2bf(acc[i][j][3]);
                    *(ushort4*)&C2[((size_t)(bb * KVN + d)) * SS + s] = p;
                }
            }
        }
    }
}

// ---------------------------------------------------------------------------
// Flash-style causal GQA attention, bf16 MFMA, Q-tile 128 rows.
// ROUND-7 RESTRUCTURE for 2 blocks/CU (round-6 profile: LDS_Block_Size=128KB
// -> only 1 block/CU, Occupancy 20%, the real binder):
//  - K is NEVER staged to LDS: each wave loads its QK fragments global->VGPR
//    per kkt (4x dwordx4; 16 rows x 64B segments; KV slice is L2-resident and
//    redundant reads total ~278 MB ~ 16% of L2 BW). Removes the 64 KB K
//    double-buffer AND all K barriers.
//  - LDS = V 32K + P 32K + mergeML 4K = 68 KB -> 2 blocks/CU, enforced by
//    __launch_bounds__(512, 4) (4 waves/SIMD = 2x 8-wave blocks).
//  - 2 barriers/tile: [vmcnt(0)+RBAR: V visible] PV [RBAR: V reads done] ->
//    stage V(t+1). V stage has a full tile of flight (drained by QK's own
//    compiler-inserted kb waits anyway).
//  - EQUAL-CHAIN task map: qc = 15-((f>>4)&15), h=f&15, b=f>>8. Co-resident
//    blocks (f,f+256 round-robin OR 2k,2k+1 sequential) get equal qc ->
//    dual residency for the entire makespan (16 dual steps vs ~17 solo).
// IN-BLOCK SPLIT-K (2 wave-groups x 4 waves, equal NT) + LDS flash merge.
// ---------------------------------------------------------------------------
__global__ __launch_bounds__(512, 4) void attn_mfma(const u16* __restrict__ Qg,
                                                    const u16* __restrict__ Kg,
                                                    const u16* __restrict__ VtG,
                                                    u16* __restrict__ ctx) {
    // carve one 68 KB region: V [2grp][128*64] | P [2grp][128*64] | ML (4 KB)
    __shared__ __align__(16) u16 SH[2 * 128 * 64 + 2 * 128 * 64 + 2048];
    u16* VtL = SH;                        // + grp*8192
    u16* PsL = SH + 2 * 128 * 64;         // + grp*8192

    const int tid  = threadIdx.x;        // 0..511
    const int w    = tid >> 6;           // 0..7
    const int grp  = w >> 2;             // wave-group: 0 = low keys, 1 = high keys
    const int wq   = w & 3;              // q-row wave within group
    const int tg   = tid & 255;          // tid within group
    const int lane = tid & 63;
    const int l16  = lane & 15;
    const int quad = lane >> 4;
    const int sw   = l16 & 7;            // swizzle key (V/P fragment rows)

    // equal-chain task map (robust to round-robin and sequential pairing)
    const int f   = blockIdx.x;                // 0..511
    const int qc  = 15 - ((f >> 4) & 15);      // descending chains
    const int h   = f & 15;
    const int b   = f >> 8;
    const int kvh = h / GG;
    const int q0  = qc * 128;
    const int NT  = qc + 1;                    // k-tiles per group (equal!)

    const size_t kgbase = (size_t)(b * SS) * KVN + kvh * DD;
    const size_t vgbase = (size_t)(b * KVN + kvh * DD) * SS;

    const int myq[2] = { q0 + wq * 16 + l16, q0 + 64 + wq * 16 + l16 };

    // ---- Q fragments direct from global ----
    bf16x8 Qa[2][4];
#pragma unroll
    for (int mi = 0; mi < 2; ++mi)
#pragma unroll
        for (int kd = 0; kd < 4; ++kd)
            Qa[mi][kd] = *(const bf16x8*)(Qg + (size_t)(b * SS + myq[mi]) * EE
                                          + h * DD + kd * 32 + quad * 8);

    float m_i[2] = {-INFINITY, -INFINITY};
    float l_i[2] = {0.f, 0.f};          // per-lane partials, reduced at the end
    f32x4 acc_o[2][8];
#pragma unroll
    for (int mi = 0; mi < 2; ++mi)
#pragma unroll
        for (int dt = 0; dt < 8; ++dt) acc_o[mi][dt] = (f32x4){0.f, 0.f, 0.f, 0.f};

    // ---- swizzled async V stage (per group, 4 waves; 4 loads/thread) ----
    auto stageV = [&](int gkt) {
#pragma unroll
        for (int it = 0; it < 4; ++it) {
            int ci = it * 256 + tg;
            int r = ci >> 3, pp = ci & 7;
            int c = (pp ^ r) & 7;
            gload_lds16(VtG + vgbase + (size_t)r * SS + gkt * 64 + c * 8,
                        &VtL[grp * 8192 + (size_t)(it * 256 + (tg & 192)) * 8]);
        }
    };

    stageV(grp * NT);                    // V(0); drained by QK's kb waits

    for (int kt = 0; kt < NT; ++kt) {
        const int gkt = grp * NT + kt;        // global 64-key tile index
        const int gk0 = gkt * 64;             // first key of this tile
        const bool hasNext = (kt + 1 < NT);   // uniform across ALL waves

        // per-mi status (wave-uniform): fully-masked / diagonal
        bool skip[2], diag[2];
#pragma unroll
        for (int mi = 0; mi < 2; ++mi) {
            const int lo = q0 + mi * 64;
            skip[mi] = (gk0 > lo + 63);
            diag[mi] = (!skip[mi]) && (gk0 + 63 > lo);
        }

        // ---- S^T = K Q^T, K fragments straight from global (L2-hot) ----
        // lane q=l16, k = gk0 + kkt*16 + quad*4 + reg
        f32x4 sc[2][4];
#pragma unroll
        for (int mi = 0; mi < 2; ++mi)
#pragma unroll
            for (int kkt = 0; kkt < 4; ++kkt) sc[mi][kkt] = (f32x4){0.f, 0.f, 0.f, 0.f};
        __builtin_amdgcn_s_setprio(1);
#pragma unroll
        for (int kkt = 0; kkt < 4; ++kkt) {
            const u16* kp = Kg + kgbase + (size_t)(gk0 + kkt * 16 + l16) * KVN + quad * 8;
            bf16x8 kb[4];
#pragma unroll
            for (int kd = 0; kd < 4; ++kd)
                kb[kd] = *(const bf16x8*)(kp + kd * 32);
            if (!skip[1])
#pragma unroll
                for (int kd = 0; kd < 4; ++kd)
                    sc[1][kkt] = __builtin_amdgcn_mfma_f32_16x16x32_bf16(kb[kd], Qa[1][kd], sc[1][kkt], 0, 0, 0);
            if (!skip[0])
#pragma unroll
                for (int kd = 0; kd < 4; ++kd)
                    sc[0][kkt] = __builtin_amdgcn_mfma_f32_16x16x32_bf16(kb[kd], Qa[0][kd], sc[0][kkt], 0, 0, 0);
        }
        __builtin_amdgcn_s_setprio(0);

        // ---- per-lane online softmax (log2 domain), vote-gated rescale ----
#pragma unroll
        for (int mi = 0; mi < 2; ++mi) {
            if (skip[mi]) continue;
            if (diag[mi]) {
                const int kb0 = gk0 + quad * 4;
#pragma unroll
                for (int kkt = 0; kkt < 4; ++kkt)
#pragma unroll
                    for (int reg = 0; reg < 4; ++reg)
                        if (kb0 + kkt * 16 + reg > myq[mi]) sc[mi][kkt][reg] = -INFINITY;
            }
            float rowmax = -INFINITY;
#pragma unroll
            for (int kkt = 0; kkt < 4; ++kkt)
                rowmax = fmaxf(rowmax,
                               fmaxf(fmaxf(sc[mi][kkt][0], sc[mi][kkt][1]),
                                     fmaxf(sc[mi][kkt][2], sc[mi][kkt][3])));

            if (__any(rowmax > m_i[mi] + 8.0f)) {   // wave-uniform, rare after warmup
                float gmax = fmaxf(rowmax, __shfl_xor(rowmax, 16, 64));
                gmax = fmaxf(gmax, __shfl_xor(gmax, 32, 64));
                float mnew = fmaxf(m_i[mi], gmax);
                float al = exp2f(m_i[mi] - mnew);
                m_i[mi] = mnew;
                l_i[mi] *= al;
#pragma unroll
                for (int dt = 0; dt < 8; ++dt)
#pragma unroll
                    for (int reg = 0; reg < 4; ++reg)
                        acc_o[mi][dt][reg] *= al;
            }

            float rsum = 0.f;
#pragma unroll
            for (int kkt = 0; kkt < 4; ++kkt)
#pragma unroll
                for (int reg = 0; reg < 4; ++reg) {
                    float p = exp2f(sc[mi][kkt][reg] - m_i[mi]);   // bounded by 2^8
                    sc[mi][kkt][reg] = p;
                    rsum += p;
                }
            l_i[mi] += rsum;

            // swizzled packed P^T write via HW cvt_pk (read only by own wave)
            const int prow = mi * 64 + wq * 16 + l16;
#pragma unroll
            for (int kkt = 0; kkt < 4; ++kkt) {
                int ch = (kkt * 2 + (quad >> 1)) ^ sw;
                uint2 pk;
                pk.x = cvtpk_bf16(sc[mi][kkt][0], sc[mi][kkt][1]);
                pk.y = cvtpk_bf16(sc[mi][kkt][2], sc[mi][kkt][3]);
                *(uint2*)&PsL[grp * 8192 + (prow * 8 + ch) * 8 + (quad & 1) * 4] = pk;
            }
        }

        // V(t) landed (own loads mostly drained already by QK's kb waits)
        asm volatile("s_waitcnt vmcnt(0)" ::: "memory");
        RBAR;                                  // V(t) visible to all waves

        // ---- O^T += V^T P^T ----
        const u16* vb_base = &VtL[grp * 8192];
        __builtin_amdgcn_s_setprio(1);
#pragma unroll
        for (int ks = 0; ks < 2; ++ks) {
            const int pc = (ks * 4 + quad) ^ sw;
            bf16x8 pb1, pb0;
            if (!skip[1]) pb1 = *(const bf16x8*)&PsL[grp * 8192 + ((64 + wq * 16 + l16) * 8 + pc) * 8];
            if (!skip[0]) pb0 = *(const bf16x8*)&PsL[grp * 8192 + ((wq * 16 + l16) * 8 + pc) * 8];
#pragma unroll
            for (int dt = 0; dt < 8; ++dt) {
                bf16x8 va = *(const bf16x8*)&vb_base[((dt * 16 + l16) * 8 + pc) * 8];
                if (!skip[1])
                    acc_o[1][dt] = __builtin_amdgcn_mfma_f32_16x16x32_bf16(va, pb1, acc_o[1][dt], 0, 0, 0);
                if (!skip[0])
                    acc_o[0][dt] = __builtin_amdgcn_mfma_f32_16x16x32_bf16(va, pb0, acc_o[0][dt], 0, 0, 0);
            }
        }
        __builtin_amdgcn_s_setprio(0);

        RBAR;                                  // all waves' V reads retired
        if (hasNext) stageV(gkt + 1);          // full tile of flight
    }

    // ---- in-block flash merge of the two key-halves ----
    __syncthreads();                          // full drain OK here (once)
    float* dumpO  = (float*)SH;               // 64 KB (reuses V+P regions)
    float* dumpML = (float*)(SH + 4 * 128 * 64);   // separate 4 KB
    if (grp == 1) {
        const int base = (wq * 64 + lane) * 64;
#pragma unroll
        for (int mi = 0; mi < 2; ++mi)
#pragma unroll
            for (int dt = 0; dt < 8; ++dt)
                *(f32x4*)&dumpO[base + mi * 32 + dt * 4] = acc_o[mi][dt];
        const int mb = (wq * 64 + lane) * 4;
        dumpML[mb + 0] = m_i[0];
        dumpML[mb + 1] = m_i[1];
        dumpML[mb + 2] = l_i[0];
        dumpML[mb + 3] = l_i[1];
    }
    __syncthreads();                          // dump visible
    if (grp == 0) {
        const int base = (wq * 64 + lane) * 64;
        const int mb = (wq * 64 + lane) * 4;
#pragma unroll
        for (int mi = 0; mi < 2; ++mi) {
            const float m1 = dumpML[mb + mi];
            const float l1 = dumpML[mb + 2 + mi];
            const float ms = fmaxf(m_i[mi], m1);
            const float a0 = exp2f(m_i[mi] - ms);   // 0 if m_i = -inf
            const float a1 = exp2f(m1 - ms);        // 0 if m1  = -inf
            float lt = l_i[mi] * a0 + l1 * a1;
            lt += __shfl_xor(lt, 16, 64);
            lt += __shfl_xor(lt, 32, 64);
            const float linv = 1.f / lt;
            u16* dst = ctx + (size_t)(b * SS + myq[mi]) * EE + h * DD;
#pragma unroll
            for (int dt = 0; dt < 8; ++dt) {
                f32x4 o1 = *(const f32x4*)&dumpO[base + mi * 32 + dt * 4];
                uint2 o;
                o.x = cvtpk_bf16((acc_o[mi][dt][0] * a0 + o1[0] * a1) * linv,
                                 (acc_o[mi][dt][1] * a0 + o1[1] * a1) * linv);
                o.y = cvtpk_bf16((acc_o[mi][dt][2] * a0 + o1[2] * a1) * linv,
                                 (acc_o[mi][dt][3] * a0 + o1[3] * a1) * linv);
                *(uint2*)&dst[dt * 16 + quad * 4] = o;
            }
        }
    }
}

// ---------------------------------------------------------------------------
extern "C" void kernel_launch(void* const* d_in, const int* in_sizes, int n_in,
                              void* d_out, int out_size, void* d_ws, size_t ws_size,
                              hipStream_t stream) {
    const float* x  = (const float*)d_in[0];
    const float* Wq = (const float*)d_in[1];
    const float* Wk = (const float*)d_in[2];
    const float* Wv = (const float*)d_in[3];
    const float* Wo = (const float*)d_in[4];
    float* out = (float*)d_out;

    const int M = BB * SS;                        // 4096
    u16* xb  = (u16*)d_ws;                        // M*E
    u16* Wqb = xb  + (size_t)M * EE;              // E*E   } contiguous ->
    u16* Wkb = Wqb + (size_t)EE * EE;             // KVN*E }  single 3072-row
    u16* Wvb = Wkb + (size_t)KVN * EE;            // KVN*E }  B matrix
    u16* Wob = Wvb + (size_t)KVN * EE;             // E*E
    u16* Qg  = Wob + (size_t)EE * EE;             // M*E (pre-scaled by QSCALE)
    u16* Kg  = Qg  + (size_t)M * EE;              // M*KVN
    u16* VtG = Kg  + (size_t)M * KVN;             // M*KVN (transposed)
    u16* ctx = VtG + (size_t)M * KVN;             // M*E

    dim3 blk(256);
    cast_all<<<dim3(NB_X + NB_QO + 2 * NB_KV + NB_QO), blk, 0, stream>>>(
        x, Wq, Wk, Wv, Wo, xb, Wqb, Wkb, Wvb, Wob);

    // fused QKV projection: B = [Wq;Wk;Wv] (3072 x 2048), m97 128-tiles
    gemm_mfma<5><<<dim3(3072 / 128, M / 128), blk, 0, stream>>>(
        xb, Wqb, Qg, Kg, VtG, M, 3072, EE);
    attn_mfma<<<dim3(512), dim3(512), 0, stream>>>(Qg, Kg, VtG, ctx);
    gemm_mfma<0><<<dim3(EE / 128, M / 128), blk, 0, stream>>>(
        ctx, Wob, out, nullptr, nullptr, M, EE, EE);
}

// Round 8
// 319.046 us; speedup vs baseline: 2.2261x; 2.2261x over previous
//
#include <hip/hip_runtime.h>
#include <math.h>

#define BB 2
#define SS 2048
#define EE 2048
#define HH 16
#define KVHH 4
#define DD 128
#define GG (HH / KVHH)
#define KVN (KVHH * DD)   // 512
#define SCALE 0.08838834764831843f
// SCALE * log2(e): scores land in log2 domain -> exp2f softmax
#define QSCALE (0.08838834764831843f * 1.4426950408889634f)

typedef __attribute__((ext_vector_type(8))) short bf16x8;
typedef __attribute__((ext_vector_type(4))) float f32x4;
typedef unsigned short u16;
typedef unsigned int u32;

__device__ __forceinline__ u16 f2bf(float f) {
    union { float f; u32 u; } x; x.f = f;
    u32 r = x.u + 0x7fff + ((x.u >> 16) & 1);   // RNE
    return (u16)(r >> 16);
}
// HW packed f32->bf16 (RNE), 1 instr for 2 values: lo=bf16(a), hi=bf16(b)
__device__ __forceinline__ u32 cvtpk_bf16(float a, float b) {
    u32 r;
    asm("v_cvt_pk_bf16_f32 %0, %1, %2" : "=v"(r) : "v"(a), "v"(b));
    return r;
}

__device__ __forceinline__ void gload_lds16(const void* g, void* l) {
    __builtin_amdgcn_global_load_lds(
        (const __attribute__((address_space(1))) u32*)g,
        (__attribute__((address_space(3))) u32*)l, 16, 0, 0);
}

// ---------------------------------------------------------------------------
// Fused fp32->bf16 cast of all 5 tensors. Block-granular segments, 1024 el/blk.
// ---------------------------------------------------------------------------
#define NB_X  8192      // B*S*E / 1024
#define NB_QO 4096      // E*E / 1024
#define NB_KV 1024      // KVN*E / 1024
__global__ __launch_bounds__(256) void cast_all(const float* __restrict__ x,
                                                const float* __restrict__ wq,
                                                const float* __restrict__ wk,
                                                const float* __restrict__ wv,
                                                const float* __restrict__ wo,
                                                u16* __restrict__ xb, u16* __restrict__ wqb,
                                                u16* __restrict__ wkb, u16* __restrict__ wvb,
                                                u16* __restrict__ wob) {
    int bid = blockIdx.x;
    const float* src; u16* dst; int off;
    if (bid < NB_X)                       { src = x;  dst = xb;  off = bid * 1024; }
    else if (bid < NB_X + NB_QO)          { src = wq; dst = wqb; off = (bid - NB_X) * 1024; }
    else if (bid < NB_X + NB_QO + NB_KV)  { src = wk; dst = wkb; off = (bid - NB_X - NB_QO) * 1024; }
    else if (bid < NB_X + NB_QO + 2*NB_KV){ src = wv; dst = wvb; off = (bid - NB_X - NB_QO - NB_KV) * 1024; }
    else                                  { src = wo; dst = wob; off = (bid - NB_X - NB_QO - 2*NB_KV) * 1024; }
    int i = off + threadIdx.x * 4;
    float4 v = *(const float4*)&src[i];
    ushort4 o;
    o.x = f2bf(v.x); o.y = f2bf(v.y); o.z = f2bf(v.z); o.w = f2bf(v.w);
    *(ushort4*)&dst[i] = o;
}

// ---------------------------------------------------------------------------
// m97-structure MFMA GEMM (PROVEN: 83 us MODE5 / ~55 us MODE0 in round 3).
// C[M,N] = A[M,K] @ B[N,K]^T, bf16 in, fp32 acc.
// MODE 0: fp32 row-major C
// MODE 5: fused QKV epilogue (B = [Wq;Wk;Wv] concat, N=3072):
//   n<2048      -> Qg bf16 [M][2048], scaled by QSCALE
//   2048..2559  -> Kg bf16 [M][512]
//   2560..3071  -> Vt bf16 [(b*KVN + d)][S]
// ---------------------------------------------------------------------------
template <int MODE>
__global__ __launch_bounds__(256) void gemm_mfma(const u16* __restrict__ A,
                                                 const u16* __restrict__ B,
                                                 void* __restrict__ Cv,
                                                 void* __restrict__ Cv2,
                                                 void* __restrict__ Cv3,
                                                 int M, int N, int K) {
    __shared__ __align__(16) u16 As[128 * 32];
    __shared__ __align__(16) u16 Bs[128 * 32];
    const int tid  = threadIdx.x;
    const int w    = tid >> 6;
    const int lane = tid & 63;
    const int l16  = lane & 15;
    const int quad = lane >> 4;
    const int wm = (w >> 1) * 64;
    const int wn = (w & 1) * 64;
    const int m0 = blockIdx.y * 128;
    const int n0 = blockIdx.x * 128;

    const int r0 = tid >> 2,           ko0 = (tid & 3) * 8;
    const int r1 = (256 + tid) >> 2,   ko1 = (tid & 3) * 8;
    u16* ldsA0 = &As[(size_t)(w * 64) * 8];
    u16* ldsA1 = &As[(size_t)(256 + w * 64) * 8];
    u16* ldsB0 = &Bs[(size_t)(w * 64) * 8];
    u16* ldsB1 = &Bs[(size_t)(256 + w * 64) * 8];

    f32x4 acc[4][4];
#pragma unroll
    for (int i = 0; i < 4; ++i)
#pragma unroll
        for (int j = 0; j < 4; ++j) acc[i][j] = (f32x4){0.f, 0.f, 0.f, 0.f};

    for (int k0 = 0; k0 < K; k0 += 32) {
        __syncthreads();
        gload_lds16(A + (size_t)(m0 + r0) * K + k0 + ko0, ldsA0);
        gload_lds16(A + (size_t)(m0 + r1) * K + k0 + ko1, ldsA1);
        gload_lds16(B + (size_t)(n0 + r0) * K + k0 + ko0, ldsB0);
        gload_lds16(B + (size_t)(n0 + r1) * K + k0 + ko1, ldsB1);
        __syncthreads();

        bf16x8 af[4], bfr[4];
#pragma unroll
        for (int i = 0; i < 4; ++i)
            af[i] = *(const bf16x8*)&As[(wm + i * 16 + l16) * 32 + quad * 8];
#pragma unroll
        for (int j = 0; j < 4; ++j)
            bfr[j] = *(const bf16x8*)&Bs[(wn + j * 16 + l16) * 32 + quad * 8];
#pragma unroll
        for (int i = 0; i < 4; ++i)
#pragma unroll
            for (int j = 0; j < 4; ++j)
                acc[i][j] = __builtin_amdgcn_mfma_f32_16x16x32_bf16(af[i], bfr[j], acc[i][j], 0, 0, 0);
    }

    if (MODE == 0) {
        float* C = (float*)Cv;
#pragma unroll
        for (int i = 0; i < 4; ++i)
#pragma unroll
            for (int j = 0; j < 4; ++j)
#pragma unroll
                for (int reg = 0; reg < 4; ++reg)
                    C[(size_t)(m0 + wm + i * 16 + quad * 4 + reg) * N + n0 + wn + j * 16 + l16] =
                        acc[i][j][reg];
    } else {   // MODE 5
        if (n0 < 2048) {
            u16* C = (u16*)Cv;   // Qg [M][2048], QSCALE folded in
#pragma unroll
            for (int i = 0; i < 4; ++i)
#pragma unroll
                for (int j = 0; j < 4; ++j)
#pragma unroll
                    for (int reg = 0; reg < 4; ++reg)
                        C[(size_t)(m0 + wm + i * 16 + quad * 4 + reg) * 2048 + n0 + wn + j * 16 + l16] =
                            f2bf(acc[i][j][reg] * QSCALE);
        } else if (n0 < 2560) {
            u16* C = (u16*)Cv2;  // Kg [M][512]
            const int nb = n0 - 2048;
#pragma unroll
            for (int i = 0; i < 4; ++i)
#pragma unroll
                for (int j = 0; j < 4; ++j)
#pragma unroll
                    for (int reg = 0; reg < 4; ++reg)
                        C[(size_t)(m0 + wm + i * 16 + quad * 4 + reg) * KVN + nb + wn + j * 16 + l16] =
                            f2bf(acc[i][j][reg]);
        } else {
            u16* C2 = (u16*)Cv3;  // Vt [(b*KVN + d)][S]
            const int db = n0 - 2560;
#pragma unroll
            for (int i = 0; i < 4; ++i) {
                const int m = m0 + wm + i * 16 + quad * 4;
                const int bb = m >> 11;
                const int s  = m & (SS - 1);
#pragma unroll
                for (int j = 0; j < 4; ++j) {
                    const int d = db + wn + j * 16 + l16;
                    ushort4 p;
                    p.x = f2bf(acc[i][j][0]); p.y = f2bf(acc[i][j][1]);
                    p.z = f2bf(acc[i][j][2]); p.w = f2bf(acc[i][j][3]);
                    *(ushort4*)&C2[((size_t)(bb * KVN + d)) * SS + s] = p;
                }
            }
        }
    }
}

// ---------------------------------------------------------------------------
// Flash-style causal GQA attention, bf16 MFMA, Q-tile 128 rows.
// IN-BLOCK SPLIT-K (2 wave-groups x 4 waves, equal NT) with the two groups
// DE-SYNCHRONIZED: groups share no LDS/data until the final merge, so the
// block-wide s_barriers (which forced 8-wave lockstep, ~12.7K cyc/tile) are
// replaced by per-group LDS monotone-counter syncs. This reproduces the
// round-2 regime of two independent 4-wave streams per CU (measured ~6.6K
// cyc/tile there) while keeping split-K's halved 16-tile chains and the
// free in-block flash merge.
//   gsync: each wave does counted s_waitcnt vmcnt(N) (its DMA landed), then
//   lane0 ds_add(+1) on gcnt[grp]; all lanes spin until gcnt >= 4*epoch
//   (s_sleep in loop; sched_barrier(0) fence after — rule #18). Counter
//   monotone -> no reset races; equal NT -> no deadlock.
//   per-tile ledger (4 loads per stage): entry vmcnt(4) confirms K(t);
//   gsync; stageK(t+1); QK+softmax+P(own-wave); vmcnt(4|0) confirms V(t);
//   gsync; PV; gsync (V reads retired); stageV(t+1).
// ---------------------------------------------------------------------------
__global__ __launch_bounds__(512, 2) void attn_mfma(const u16* __restrict__ Qg,
                                                    const u16* __restrict__ Kg,
                                                    const u16* __restrict__ VtG,
                                                    u16* __restrict__ ctx) {
    __shared__ __align__(16) u16 Ks[2][2][64 * 128];   // [grp][buf] 64 KB
    __shared__ __align__(16) u16 Vt[2][128 * 64];      // [grp] 32 KB
    __shared__ __align__(16) u16 Ps[2][128 * 64];      // [grp] 32 KB
    __shared__ u32 gcnt[2];                            // per-group sync counters

    const int tid  = threadIdx.x;        // 0..511
    const int w    = tid >> 6;           // 0..7
    const int grp  = w >> 2;             // wave-group: 0 = low keys, 1 = high keys
    const int wq   = w & 3;              // q-row wave within group
    const int tg   = tid & 255;          // tid within group
    const int lane = tid & 63;
    const int l16  = lane & 15;
    const int quad = lane >> 4;
    const int sw   = l16 & 7;            // swizzle key for all fragment rows

    // task map: blocks f and f+256 get qc summing to 15 (small first, then big)
    const int f    = blockIdx.x;
    const int half = f >> 8;
    const int u    = f & 255;
    const int h    = u & 15;
    const int w2   = u >> 4;
    const int b    = w2 & 1;
    const int j    = w2 >> 1;                  // 0..7
    const int qc   = half ? (15 - j) : j;      // 0..15
    const int kvh  = h / GG;
    const int q0   = qc * 128;
    const int NT   = qc + 1;                   // k-tiles per group (equal!)

    const size_t kgbase = (size_t)(b * SS) * KVN + kvh * DD;
    const size_t vgbase = (size_t)(b * KVN + kvh * DD) * SS;

    const int myq[2] = { q0 + wq * 16 + l16, q0 + 64 + wq * 16 + l16 };

    // ---- init per-group sync counters (once, before any DMA) ----
    if (tid < 2) gcnt[tid] = 0;
    __syncthreads();

    // per-group sync: epoch target = 4 waves * epoch
    int ep = 0;
    auto gsync = [&]() {
        ++ep;
        const u32 tgt = (u32)(4 * ep);
        if (lane == 0) atomicAdd(&gcnt[grp], 1u);
        while (*(volatile u32*)&gcnt[grp] < tgt) __builtin_amdgcn_s_sleep(1);
        __builtin_amdgcn_sched_barrier(0);   // pin LDS reads after the spin exit
    };

    // ---- Q fragments direct from global (oldest vmem ops) ----
    bf16x8 Qa[2][4];
#pragma unroll
    for (int mi = 0; mi < 2; ++mi)
#pragma unroll
        for (int kd = 0; kd < 4; ++kd)
            Qa[mi][kd] = *(const bf16x8*)(Qg + (size_t)(b * SS + myq[mi]) * EE
                                          + h * DD + kd * 32 + quad * 8);

    float m_i[2] = {-INFINITY, -INFINITY};
    float l_i[2] = {0.f, 0.f};          // per-lane partials, reduced at the end
    f32x4 acc_o[2][8];
#pragma unroll
    for (int mi = 0; mi < 2; ++mi)
#pragma unroll
        for (int dt = 0; dt < 8; ++dt) acc_o[mi][dt] = (f32x4){0.f, 0.f, 0.f, 0.f};

    // ---- swizzled async stages (per group, 4 waves each; 4 loads/thread) ----
    auto stageK = [&](int gkt, int buf) {
#pragma unroll
        for (int it = 0; it < 4; ++it) {
            int ci = it * 256 + tg;           // chunk slot (16B units), 1024 total
            int r = ci >> 4, pp = ci & 15;
            int c = (pp & 8) | ((pp ^ r) & 7);
            gload_lds16(Kg + kgbase + (size_t)(gkt * 64 + r) * KVN + c * 8,
                        &Ks[grp][buf][(size_t)(it * 256 + (tg & 192)) * 8]);
        }
    };
    auto stageV = [&](int gkt) {
#pragma unroll
        for (int it = 0; it < 4; ++it) {
            int ci = it * 256 + tg;
            int r = ci >> 3, pp = ci & 7;
            int c = (pp ^ r) & 7;
            gload_lds16(VtG + vgbase + (size_t)r * SS + gkt * 64 + c * 8,
                        &Vt[grp][(size_t)(it * 256 + (tg & 192)) * 8]);
        }
    };

    // ---- prologue: stage K(0), V(0); confirm Qa (leave 8 DMA in flight) ----
    stageK(grp * NT, 0);
    stageV(grp * NT);
    asm volatile("s_waitcnt vmcnt(8)" ::: "memory");
    int buf = 0;

    for (int kt = 0; kt < NT; ++kt) {
        const int gkt = grp * NT + kt;        // global 64-key tile index
        const int gk0 = gkt * 64;             // first key of this tile
        const bool hasNext = (kt + 1 < NT);   // uniform within the group

        // entry ledger: {K(t):4 oldest, V(t):4}
        asm volatile("s_waitcnt vmcnt(4)" ::: "memory");   // K(t) landed (own wave)
        gsync();                                           // ... and group-wide

        // prefetch next K into the idle buffer
        if (hasNext) stageK(gkt + 1, buf ^ 1);   // ledger: {V(t):4, K(t+1):4}

        // per-mi status (wave-uniform): fully-masked / diagonal
        bool skip[2], diag[2];
#pragma unroll
        for (int mi = 0; mi < 2; ++mi) {
            const int lo = q0 + mi * 64;
            skip[mi] = (gk0 > lo + 63);
            diag[mi] = (!skip[mi]) && (gk0 + 63 > lo);
        }

        const u16* kb_base = Ks[grp][buf];

        // ---- S^T = K Q^T : lane q=l16, k = gk0 + kkt*16 + quad*4 + reg ----
        f32x4 sc[2][4];
#pragma unroll
        for (int mi = 0; mi < 2; ++mi)
#pragma unroll
            for (int kkt = 0; kkt < 4; ++kkt) sc[mi][kkt] = (f32x4){0.f, 0.f, 0.f, 0.f};
        __builtin_amdgcn_s_setprio(1);
#pragma unroll
        for (int kkt = 0; kkt < 4; ++kkt) {
            const int R = kkt * 16 + l16;
            bf16x8 kb[4];
#pragma unroll
            for (int kd = 0; kd < 4; ++kd) {
                int c = kd * 4 + quad;
                int pp = (c & 8) | ((c ^ sw) & 7);
                kb[kd] = *(const bf16x8*)&kb_base[(R * 16 + pp) * 8];
            }
            if (!skip[1])
#pragma unroll
                for (int kd = 0; kd < 4; ++kd)
                    sc[1][kkt] = __builtin_amdgcn_mfma_f32_16x16x32_bf16(kb[kd], Qa[1][kd], sc[1][kkt], 0, 0, 0);
            if (!skip[0])
#pragma unroll
                for (int kd = 0; kd < 4; ++kd)
                    sc[0][kkt] = __builtin_amdgcn_mfma_f32_16x16x32_bf16(kb[kd], Qa[0][kd], sc[0][kkt], 0, 0, 0);
        }
        __builtin_amdgcn_s_setprio(0);

        // ---- per-lane online softmax (log2 domain), vote-gated rescale ----
#pragma unroll
        for (int mi = 0; mi < 2; ++mi) {
            if (skip[mi]) continue;
            if (diag[mi]) {
                const int kb0 = gk0 + quad * 4;
#pragma unroll
                for (int kkt = 0; kkt < 4; ++kkt)
#pragma unroll
                    for (int reg = 0; reg < 4; ++reg)
                        if (kb0 + kkt * 16 + reg > myq[mi]) sc[mi][kkt][reg] = -INFINITY;
            }
            float rowmax = -INFINITY;
#pragma unroll
            for (int kkt = 0; kkt < 4; ++kkt)
                rowmax = fmaxf(rowmax,
                               fmaxf(fmaxf(sc[mi][kkt][0], sc[mi][kkt][1]),
                                     fmaxf(sc[mi][kkt][2], sc[mi][kkt][3])));

            if (__any(rowmax > m_i[mi] + 8.0f)) {   // wave-uniform, rare after warmup
                float gmax = fmaxf(rowmax, __shfl_xor(rowmax, 16, 64));
                gmax = fmaxf(gmax, __shfl_xor(gmax, 32, 64));
                float mnew = fmaxf(m_i[mi], gmax);
                float al = exp2f(m_i[mi] - mnew);
                m_i[mi] = mnew;
                l_i[mi] *= al;
#pragma unroll
                for (int dt = 0; dt < 8; ++dt)
#pragma unroll
                    for (int reg = 0; reg < 4; ++reg)
                        acc_o[mi][dt][reg] *= al;
            }

            float rsum = 0.f;
#pragma unroll
            for (int kkt = 0; kkt < 4; ++kkt)
#pragma unroll
                for (int reg = 0; reg < 4; ++reg) {
                    float p = exp2f(sc[mi][kkt][reg] - m_i[mi]);   // bounded by 2^8
                    sc[mi][kkt][reg] = p;
                    rsum += p;
                }
            l_i[mi] += rsum;

            // swizzled packed P^T write via HW cvt_pk (read only by own wave)
            const int prow = mi * 64 + wq * 16 + l16;
#pragma unroll
            for (int kkt = 0; kkt < 4; ++kkt) {
                int ch = (kkt * 2 + (quad >> 1)) ^ sw;
                uint2 pk;
                pk.x = cvtpk_bf16(sc[mi][kkt][0], sc[mi][kkt][1]);
                pk.y = cvtpk_bf16(sc[mi][kkt][2], sc[mi][kkt][3]);
                *(uint2*)&Ps[grp][(prow * 8 + ch) * 8 + (quad & 1) * 4] = pk;
            }
        }

        // confirm V(t): oldest 4 of {V(t):4, K(t+1):4}; last iter drain to 0
        if (hasNext) { asm volatile("s_waitcnt vmcnt(4)" ::: "memory"); }
        else         { asm volatile("s_waitcnt vmcnt(0)" ::: "memory"); }
        gsync();                               // V(t) visible group-wide

        // ---- O^T += V^T P^T ----
        const u16* vb_base = Vt[grp];
        __builtin_amdgcn_s_setprio(1);
#pragma unroll
        for (int ks = 0; ks < 2; ++ks) {
            const int pc = (ks * 4 + quad) ^ sw;
            bf16x8 pb1, pb0;
            if (!skip[1]) pb1 = *(const bf16x8*)&Ps[grp][((64 + wq * 16 + l16) * 8 + pc) * 8];
            if (!skip[0]) pb0 = *(const bf16x8*)&Ps[grp][((wq * 16 + l16) * 8 + pc) * 8];
#pragma unroll
            for (int dt = 0; dt < 8; ++dt) {
                bf16x8 va = *(const bf16x8*)&vb_base[((dt * 16 + l16) * 8 + pc) * 8];
                if (!skip[1])
                    acc_o[1][dt] = __builtin_amdgcn_mfma_f32_16x16x32_bf16(va, pb1, acc_o[1][dt], 0, 0, 0);
                if (!skip[0])
                    acc_o[0][dt] = __builtin_amdgcn_mfma_f32_16x16x32_bf16(va, pb0, acc_o[0][dt], 0, 0, 0);
            }
        }
        __builtin_amdgcn_s_setprio(0);

        gsync();                               // group's V reads retired
        if (hasNext) stageV(gkt + 1);          // full tile of flight
        buf ^= 1;
    }

    // ---- in-block flash merge of the two key-halves ----
    __syncthreads();                          // re-converge both groups (drain OK)
    float* dumpO = (float*)&Ks[0][0][0];      // 4 waves * 64 lanes * 64 f32 = 64 KB
    float* dumpML = (float*)&Ps[1][0];        // 4 waves * 64 lanes * 4 f32 = 4 KB
    if (grp == 1) {
        const int base = (wq * 64 + lane) * 64;
#pragma unroll
        for (int mi = 0; mi < 2; ++mi)
#pragma unroll
            for (int dt = 0; dt < 8; ++dt)
                *(f32x4*)&dumpO[base + mi * 32 + dt * 4] = acc_o[mi][dt];
        const int mb = (wq * 64 + lane) * 4;
        dumpML[mb + 0] = m_i[0];
        dumpML[mb + 1] = m_i[1];
        dumpML[mb + 2] = l_i[0];
        dumpML[mb + 3] = l_i[1];
    }
    __syncthreads();                          // dump visible
    if (grp == 0) {
        const int base = (wq * 64 + lane) * 64;
        const int mb = (wq * 64 + lane) * 4;
#pragma unroll
        for (int mi = 0; mi < 2; ++mi) {
            const float m1 = dumpML[mb + mi];
            const float l1 = dumpML[mb + 2 + mi];
            const float ms = fmaxf(m_i[mi], m1);
            const float a0 = exp2f(m_i[mi] - ms);   // 0 if m_i = -inf
            const float a1 = exp2f(m1 - ms);        // 0 if m1  = -inf
            float lt = l_i[mi] * a0 + l1 * a1;
            lt += __shfl_xor(lt, 16, 64);
            lt += __shfl_xor(lt, 32, 64);
            const float linv = 1.f / lt;
            u16* dst = ctx + (size_t)(b * SS + myq[mi]) * EE + h * DD;
#pragma unroll
            for (int dt = 0; dt < 8; ++dt) {
                f32x4 o1 = *(const f32x4*)&dumpO[base + mi * 32 + dt * 4];
                uint2 o;
                o.x = cvtpk_bf16((acc_o[mi][dt][0] * a0 + o1[0] * a1) * linv,
                                 (acc_o[mi][dt][1] * a0 + o1[1] * a1) * linv);
                o.y = cvtpk_bf16((acc_o[mi][dt][2] * a0 + o1[2] * a1) * linv,
                                 (acc_o[mi][dt][3] * a0 + o1[3] * a1) * linv);
                *(uint2*)&dst[dt * 16 + quad * 4] = o;
            }
        }
    }
}

// ---------------------------------------------------------------------------
extern "C" void kernel_launch(void* const* d_in, const int* in_sizes, int n_in,
                              void* d_out, int out_size, void* d_ws, size_t ws_size,
                              hipStream_t stream) {
    const float* x  = (const float*)d_in[0];
    const float* Wq = (const float*)d_in[1];
    const float* Wk = (const float*)d_in[2];
    const float* Wv = (const float*)d_in[3];
    const float* Wo = (const float*)d_in[4];
    float* out = (float*)d_out;

    const int M = BB * SS;                        // 4096
    u16* xb  = (u16*)d_ws;                        // M*E
    u16* Wqb = xb  + (size_t)M * EE;              // E*E   } contiguous ->
    u16* Wkb = Wqb + (size_t)EE * EE;             // KVN*E }  single 3072-row
    u16* Wvb = Wkb + (size_t)KVN * EE;            // KVN*E }  B matrix
    u16* Wob = Wvb + (size_t)KVN * EE;            // E*E
    u16* Qg  = Wob + (size_t)EE * EE;             // M*E (pre-scaled by QSCALE)
    u16* Kg  = Qg  + (size_t)M * EE;              // M*KVN
    u16* VtG = Kg  + (size_t)M * KVN;             // M*KVN (transposed)
    u16* ctx = VtG + (size_t)M * KVN;             // M*E

    dim3 blk(256);
    cast_all<<<dim3(NB_X + NB_QO + 2 * NB_KV + NB_QO), blk, 0, stream>>>(
        x, Wq, Wk, Wv, Wo, xb, Wqb, Wkb, Wvb, Wob);

    // fused QKV projection: B = [Wq;Wk;Wv] (3072 x 2048), m97 128-tiles
    gemm_mfma<5><<<dim3(3072 / 128, M / 128), blk, 0, stream>>>(
        xb, Wqb, Qg, Kg, VtG, M, 3072, EE);
    attn_mfma<<<dim3(512), dim3(512), 0, stream>>>(Qg, Kg, VtG, ctx);
    gemm_mfma<0><<<dim3(EE / 128, M / 128), blk, 0, stream>>>(
        ctx, Wob, out, nullptr, nullptr, M, EE, EE);
}